// Round 5
// baseline (237.954 us; speedup 1.0000x reference)
//
#include <hip/hip_runtime.h>
#include <stdint.h>
#include <stddef.h>

#define DIM 1024
#define EPS 1e-8f

typedef __attribute__((ext_vector_type(4)))  int   i32x4;
typedef __attribute__((ext_vector_type(8)))  int   i32x8;
typedef __attribute__((ext_vector_type(16))) float f32x16;

// e8m0 scale byte 123 = 2^(123-127) = 1/16 per operand -> 1/256 on the product,
// exactly cancelling the x16 prep scaling (bit-exact pow2 exponent shift).
#define SCALE8 0x7B7B7B7B

// async global->LDS, 16B per lane, wave-uniform LDS base + lane*16
__device__ __forceinline__ void async_copy16(const void* g, void* l) {
    __builtin_amdgcn_global_load_lds(
        (__attribute__((address_space(1))) void*)const_cast<void*>(g),
        (__attribute__((address_space(3))) void*)(l), 16, 0, 0);
}

// ---------------------------------------------------------------------------
// Prep: wave-per-row. Unit-normalize, scale by 16 (undone by hw e8m0 scales in
// the GEMM), cast to OCP fp8 e4m3, store rows LINEARLY with coalesced dword
// stores. The GEMM's staging-side chunk XOR supplies the LDS bank swizzle.
// ---------------------------------------------------------------------------
__global__ __launch_bounds__(256)
void prep_all(const float* __restrict__ x, const float* __restrict__ pos,
              const float* __restrict__ neg,
              unsigned char* __restrict__ Xn, unsigned char* __restrict__ Nn,
              float* __restrict__ simOut, float* __restrict__ rowsum, int bn) {
    const int lane = threadIdx.x & 63;
    const int wave = threadIdx.x >> 6;
    const int grow = blockIdx.x * 4 + wave;
    const bool isX = grow < bn;
    const int row  = isX ? grow : grow - bn;
    const float* src = isX ? x : neg;
    unsigned char* dst = isX ? Xn : Nn;

    const float4* s = (const float4*)(src + (size_t)row * DIM);
    float4 xv[4], pv[4];
    float sxx = 0.f, spp = 0.f, sxp = 0.f;
#pragma unroll
    for (int i = 0; i < 4; i++) {
        xv[i] = s[lane + 64 * i];
        sxx += xv[i].x * xv[i].x + xv[i].y * xv[i].y + xv[i].z * xv[i].z + xv[i].w * xv[i].w;
    }
    if (isX) {
        const float4* p = (const float4*)(pos + (size_t)row * DIM);
#pragma unroll
        for (int i = 0; i < 4; i++) {
            pv[i] = p[lane + 64 * i];
            spp += pv[i].x * pv[i].x + pv[i].y * pv[i].y + pv[i].z * pv[i].z + pv[i].w * pv[i].w;
            sxp += xv[i].x * pv[i].x + xv[i].y * pv[i].y + xv[i].z * pv[i].z + xv[i].w * pv[i].w;
        }
#pragma unroll
        for (int off = 1; off < 64; off <<= 1) {
            sxx += __shfl_xor(sxx, off);
            spp += __shfl_xor(spp, off);
            sxp += __shfl_xor(sxp, off);
        }
    } else {
#pragma unroll
        for (int off = 1; off < 64; off <<= 1) sxx += __shfl_xor(sxx, off);
    }
    const float nx  = sqrtf(sxx);
    const float inv = (nx > 0.f) ? (16.f / nx) : 0.f;   // x16 -> e4m3 sweet spot
    if (isX && lane == 0) {
        const float np = sqrtf(spp);
        simOut[row] = sxp / fmaxf(nx * np, EPS);
        rowsum[row] = 0.f;
    }
    unsigned int t;
    t = __builtin_amdgcn_cvt_pk_fp8_f32(xv[0].x * inv, xv[0].y * inv, 0, false);
    unsigned int q0 = __builtin_amdgcn_cvt_pk_fp8_f32(xv[0].z * inv, xv[0].w * inv, t, true);
    t = __builtin_amdgcn_cvt_pk_fp8_f32(xv[1].x * inv, xv[1].y * inv, 0, false);
    unsigned int q1 = __builtin_amdgcn_cvt_pk_fp8_f32(xv[1].z * inv, xv[1].w * inv, t, true);
    t = __builtin_amdgcn_cvt_pk_fp8_f32(xv[2].x * inv, xv[2].y * inv, 0, false);
    unsigned int q2 = __builtin_amdgcn_cvt_pk_fp8_f32(xv[2].z * inv, xv[2].w * inv, t, true);
    t = __builtin_amdgcn_cvt_pk_fp8_f32(xv[3].x * inv, xv[3].y * inv, 0, false);
    unsigned int q3 = __builtin_amdgcn_cvt_pk_fp8_f32(xv[3].z * inv, xv[3].w * inv, t, true);

    unsigned int* wr = (unsigned int*)(dst + (size_t)row * DIM);
    wr[lane]       = q0;
    wr[lane + 64]  = q1;
    wr[lane + 128] = q2;
    wr[lane + 192] = q3;
}

// ---------------------------------------------------------------------------
// Fused MX-fp8 GEMM: rowsum[i] += sum_j exp( unit(x_i) . unit(neg_j) )
// 256x256 tile, 8 waves, per-wave 128x64 = 4m x 2n frags of the
// mfma_scale_f32_32x32x64_f8f6f4 cell (R1/R2-verified layout; 2x the
// FLOP-per-LDS-byte of 16x16x128 -> fixes R4's 2:1 LDS:MFMA imbalance).
// BK=64-B k-window (16 windows), THREE-buffer rotation (96 KB dyn LDS),
// prefetch distance 2, counted s_waitcnt vmcnt(4) at window boundaries
// (never 0 until the tail) — R4's verified schedule.
// Per window per wave: 4 glds issue | 12 ds_read_b128 | setprio 8 MFMA.
// vmcnt ledger (4 glds/wave/window, in-order): prologue 8 -> wait(4);
// window w (w<=13) issues 4 for w+2, boundary wait(4) => w+1 landed, w+2
// in flight across the barrier; w=14 waits(0); w=15 computes only.
// Buffer hazard: window w stages buf (w+2)%3 = (w-1)%3, whose readers all
// passed the boundary barrier of w-1 before w's first issue.
// LDS swizzle (R2-verified): 64-B row = 4 chunks; slot p of row r holds
// logical chunk p ^ ((r>>1)&3); staging-side sch = (lane&3)^((lane>>3)&3)
// (rows 16-aligned per glds). Read: lane row=l&31, kh=l>>5 owns k-bytes
// [32kh,32kh+32) via 2 b128 at slot (2kh)^((row>>1)&3) and that ^1.
// ---------------------------------------------------------------------------
__global__ __launch_bounds__(512, 2)
void gemm_exp_rowsum(const unsigned char* __restrict__ Xn,
                     const unsigned char* __restrict__ Nn,
                     float* __restrict__ rowsum) {
    constexpr int KB   = DIM;            // 1024 bytes per fp8 row
    constexpr int BK   = 64;             // bytes per k-window (K=64 elems)
    constexpr int BOFF = 256 * BK;       // B area offset within a buffer (16 KB)
    constexpr int BUFB = 2 * BOFF;       // 32 KB per buffer (A then B)
    extern __shared__ unsigned char smem[];     // 3 * BUFB = 96 KB

    const int tid  = threadIdx.x;
    const int lane = tid & 63;
    const int wave = tid >> 6;                 // 0..7

    // T1: bijective chunked XCD swizzle (nwg = 512, divisible by 8)
    const int nwg  = gridDim.x * gridDim.y;
    const int bid  = blockIdx.y * gridDim.x + blockIdx.x;
    const int swz  = (bid & 7) * (nwg >> 3) + (bid >> 3);
    const int rowBase = (swz / gridDim.x) * 256;
    const int colBase = (swz % gridDim.x) * 256;

    // staging: one glds = 1 KB = 16 rows x 64 B. lane -> (srow=lane>>2, slot=lane&3).
    // global chunk = slot ^ ((srow>>1)&3) = (lane&3) ^ ((lane>>3)&3).
    const int srow = lane >> 2;
    const int sch  = (lane & 3) ^ ((lane >> 3) & 3);
    const unsigned char* gA = Xn + (size_t)(rowBase + wave * 32 + srow) * KB + sch * 16;
    const unsigned char* gB = Nn + (size_t)(colBase + wave * 32 + srow) * KB + sch * 16;

    f32x16 acc[4][2];
#pragma unroll
    for (int mi = 0; mi < 4; mi++)
#pragma unroll
        for (int ni = 0; ni < 2; ni++)
#pragma unroll
            for (int e = 0; e < 16; e++) acc[mi][ni][e] = 0.f;

    const int m0   = (wave >> 2) * 128;  // M-half: 0,128
    const int n0   = (wave & 3) * 64;    // N-quarter: 0,64,128,192
    const int mrow = lane & 31;          // fragment row
    const int kh   = lane >> 5;          // k-half: bytes [32kh, 32kh+32)
    const int c0   = ((2 * kh) ^ ((mrow >> 1) & 3)) << 4;   // 2nd b128 at ^16

    int aoff[4], boff[2];
#pragma unroll
    for (int i = 0; i < 4; i++) aoff[i] = (m0 + 32 * i + mrow) * BK + c0;
#pragma unroll
    for (int i = 0; i < 2; i++) boff[i] = BOFF + (n0 + 32 * i + mrow) * BK + c0;

    // wave stages A rows [wave*32, +32) and B rows [wave*32, +32): 4 glds.
#define STAGE(buf, stg)                                                        \
    do {                                                                       \
        const int kq = (stg) * BK;                                             \
        unsigned char* Lb = smem + (buf) * BUFB;                               \
        async_copy16(gA + kq,           Lb + (wave * 32) * BK);                \
        async_copy16(gA + 16 * KB + kq, Lb + (wave * 32 + 16) * BK);           \
        async_copy16(gB + kq,           Lb + BOFF + (wave * 32) * BK);         \
        async_copy16(gB + 16 * KB + kq, Lb + BOFF + (wave * 32 + 16) * BK);    \
    } while (0)

#define RD(base, off, dst)                                                     \
    do {                                                                       \
        i32x4 lo_ = *(const i32x4*)((base) + (off));                           \
        i32x4 hi_ = *(const i32x4*)((base) + ((off) ^ 16));                    \
        dst = __builtin_shufflevector(lo_, hi_, 0, 1, 2, 3, 4, 5, 6, 7);       \
    } while (0)

    // prologue: windows 0,1 in flight (8 ops); retire window 0, keep 4.
    STAGE(0, 0);
    STAGE(1, 1);
    asm volatile("s_waitcnt vmcnt(4)\n\ts_barrier" ::: "memory");

#pragma unroll
    for (int w = 0; w < 16; w++) {
        const int b = w % 3;
        const unsigned char* Ab = smem + b * BUFB;
        if (w <= 13) STAGE((w + 2) % 3, w + 2);
        i32x8 Af[4], Bf[2];
#pragma unroll
        for (int i = 0; i < 4; i++) RD(Ab, aoff[i], Af[i]);
#pragma unroll
        for (int i = 0; i < 2; i++) RD(Ab, boff[i], Bf[i]);
        __builtin_amdgcn_s_setprio(1);
#pragma unroll
        for (int mi = 0; mi < 4; mi++)
#pragma unroll
            for (int ni = 0; ni < 2; ni++)
                acc[mi][ni] = __builtin_amdgcn_mfma_scale_f32_32x32x64_f8f6f4(
                    Af[mi], Bf[ni], acc[mi][ni], 0, 0, 0, SCALE8, 0, SCALE8);
        __builtin_amdgcn_s_setprio(0);
        // window boundary: counted wait (never 0 until the tail)
        if (w <= 13) {
            asm volatile("s_waitcnt vmcnt(4)\n\ts_barrier" ::: "memory");
        } else if (w == 14) {
            asm volatile("s_waitcnt vmcnt(0)\n\ts_barrier" ::: "memory");
        }
    }
#undef STAGE
#undef RD

    // epilogue (R2-verified): 32x32 C/D layout col=lane&31,
    // row = (reg&3) + 8*(reg>>2) + 4*kh. exp, sum the 2 ni blocks, reduce
    // 32 cols per half-wave, one atomic per row per block.
#pragma unroll
    for (int mi = 0; mi < 4; mi++) {
        float rs[16];
#pragma unroll
        for (int r = 0; r < 16; r++) {
            float v = __expf(acc[mi][0][r]) + __expf(acc[mi][1][r]);
            v += __shfl_xor(v, 1);
            v += __shfl_xor(v, 2);
            v += __shfl_xor(v, 4);
            v += __shfl_xor(v, 8);
            v += __shfl_xor(v, 16);
            rs[r] = v;
        }
        if ((lane & 31) == 0) {
            const int rbase = rowBase + m0 + 32 * mi + 4 * kh;
#pragma unroll
            for (int r = 0; r < 16; r++)
                atomicAdd(&rowsum[rbase + (r & 3) + 8 * (r >> 2)], rs[r]);
        }
    }
}

__global__ __launch_bounds__(1024)
void loss_kernel(const float* __restrict__ rowsum, const float* __restrict__ sim,
                 float* __restrict__ out, int bn) {
    const int tid  = threadIdx.x;
    const int lane = tid & 63;
    const int wave = tid >> 6;
    float acc = 0.f;
    for (int i = tid; i < bn; i += 1024) acc += logf(rowsum[i]) - sim[i];
#pragma unroll
    for (int off = 1; off < 64; off <<= 1) acc += __shfl_xor(acc, off);
    __shared__ float red[16];
    if (lane == 0) red[wave] = acc;
    __syncthreads();
    if (tid == 0) {
        float t = 0.f;
#pragma unroll
        for (int i = 0; i < 16; i++) t += red[i];
        out[0] = t / (float)bn;
    }
}

extern "C" void kernel_launch(void* const* d_in, const int* in_sizes, int n_in,
                              void* d_out, int out_size, void* d_ws, size_t ws_size,
                              hipStream_t stream) {
    const float* x   = (const float*)d_in[0];
    const float* pos = (const float*)d_in[1];
    const float* neg = (const float*)d_in[2];
    const int bn = in_sizes[0] / DIM;  // 4096
    const int cn = in_sizes[2] / DIM;  // 8192

    // ws layout: Xn fp8 [bn*DIM] | Nn fp8 [cn*DIM] | sim f32 [bn] | rowsum f32 [bn]
    unsigned char* Xn = (unsigned char*)d_ws;
    unsigned char* Nn = Xn + (size_t)bn * DIM;
    float* sim    = (float*)(Nn + (size_t)cn * DIM);
    float* rowsum = sim + bn;

    // opt in to 96 KB dynamic LDS. Host-side attribute set — graph-safe.
    static bool attr_done = false;
    if (!attr_done) {
        (void)hipFuncSetAttribute((const void*)gemm_exp_rowsum,
                                  hipFuncAttributeMaxDynamicSharedMemorySize,
                                  98304);
        attr_done = true;
    }

    prep_all<<<dim3((bn + cn) / 4), dim3(256), 0, stream>>>(x, pos, neg, Xn, Nn, sim, rowsum, bn);
    gemm_exp_rowsum<<<dim3(cn / 256, bn / 256), dim3(512), 98304, stream>>>(Xn, Nn, rowsum);
    loss_kernel<<<dim3(1), dim3(1024), 0, stream>>>(rowsum, sim, (float*)d_out, bn);
}